// Round 12
// baseline (99.930 us; speedup 1.0000x reference)
//
#include <hip/hip_runtime.h>
#include <hip/hip_bf16.h>
#include <math.h>

#define T_SEQ 2048
#define NH 16
#define KVH 4
#define HD 128
#define DM 2048
#define KVD 512

typedef short bf16x8 __attribute__((ext_vector_type(8)));
typedef float f32x4 __attribute__((ext_vector_type(4)));
typedef float f32x16 __attribute__((ext_vector_type(16)));
typedef unsigned int uint2v __attribute__((ext_vector_type(2)));

static __device__ __forceinline__ unsigned short f2bf(float f) {
    unsigned int x = __float_as_uint(f);
    x += 0x7fff + ((x >> 16) & 1);   // round-to-nearest-even
    return (unsigned short)(x >> 16);
}
static __device__ __forceinline__ float bf2f(unsigned short u) {
    return __uint_as_float(((unsigned int)u) << 16);
}

static __device__ __forceinline__ unsigned int cvtpk(float lo, float hi) {
    unsigned int r;
    asm("v_cvt_pk_bf16_f32 %0, %1, %2" : "=v"(r) : "v"(lo), "v"(hi));
    return r;
}

static __device__ __forceinline__ f32x4 mfma16(bf16x8 a, bf16x8 b, f32x4 c) {
    return __builtin_amdgcn_mfma_f32_16x16x32_bf16(a, b, c, 0, 0, 0);
}
static __device__ __forceinline__ f32x16 mfma32(bf16x8 a, bf16x8 b, f32x16 c) {
    return __builtin_amdgcn_mfma_f32_32x32x16_bf16(a, b, c, 0, 0, 0);
}

// Swizzled fragment layouts (fully coalesced main-loop loads; lane offset = l*8):
//  Ks[kh][kt][sl][l][j]           : elem (t=kt*32+(l&31), d=sl*16+(l>>5)*8+j)
//  Vs[kh][kt][half*4+db][l][j]    : elem (t=kt*32+half*16+(l>>5)*8+j, c=kh*128+db*32+(l&31))

// ---------------- kernel 2: RMSNorm + RoPE (rope fused); Q row-major, K swizzled ----------------
__global__ __launch_bounds__(256) void qk_prep(
    const float* __restrict__ q, const float* __restrict__ k,
    const float* __restrict__ qw, const float* __restrict__ kw,
    const int* __restrict__ pos_ids,
    unsigned short* __restrict__ Qb, unsigned short* __restrict__ Ks) {
    __shared__ float qr[DM];
    __shared__ float kr[KVD];
    __shared__ float cosL[64], sinL[64];
    __shared__ float redq[4], redk[4];
    int t = blockIdx.x, tid = threadIdx.x;

    float qs = 0.f, ks = 0.f;
    {
        const float* qp = q + (size_t)t * DM + tid * 8;
        float4 v0 = *(const float4*)(qp);
        float4 v1 = *(const float4*)(qp + 4);
        float* dst = qr + tid * 8;
        dst[0] = v0.x; dst[1] = v0.y; dst[2] = v0.z; dst[3] = v0.w;
        dst[4] = v1.x; dst[5] = v1.y; dst[6] = v1.z; dst[7] = v1.w;
        qs = v0.x * v0.x + v0.y * v0.y + v0.z * v0.z + v0.w * v0.w +
             v1.x * v1.x + v1.y * v1.y + v1.z * v1.z + v1.w * v1.w;
        float2 kv = *(const float2*)(k + (size_t)t * KVD + tid * 2);
        kr[tid * 2] = kv.x; kr[tid * 2 + 1] = kv.y;
        ks = kv.x * kv.x + kv.y * kv.y;
    }
    if (tid < 64) {   // fused RoPE table for this token
        float pos = (float)pos_ids[t];
        float inv = powf(10000.0f, -(float)tid * (1.0f / 64.0f));
        float a = pos * inv;
        cosL[tid] = cosf(a);
        sinL[tid] = sinf(a);
    }
    for (int off = 32; off; off >>= 1) {
        qs += __shfl_down(qs, off);
        ks += __shfl_down(ks, off);
    }
    if ((tid & 63) == 0) { redq[tid >> 6] = qs; redk[tid >> 6] = ks; }
    __syncthreads();
    float qinv = rsqrtf((redq[0] + redq[1] + redq[2] + redq[3]) * (1.0f / DM) + 1e-5f);
    float kinv = rsqrtf((redk[0] + redk[1] + redk[2] + redk[3]) * (1.0f / KVD) + 1e-5f);

    {
        int base = tid * 8;
        int h = base >> 7;
        int d = base & 127;
        bool lo = d < 64;
        int i0 = d & 63;
        int pb = lo ? base + 64 : base - 64;
        #pragma unroll
        for (int j = 0; j < 8; ++j) {
            float xv = qr[base + j] * qinv * qw[base + j];
            float pv = qr[pb + j] * qinv * qw[pb + j];
            float c = cosL[i0 + j];
            float s = sinL[i0 + j];
            float o = lo ? (xv * c - pv * s) : (xv * c + pv * s);
            Qb[((size_t)h * T_SEQ + t) * HD + d + j] = f2bf(o);
        }
    }
    {
        int base = tid * 2;
        int kh = base >> 7;
        int d = base & 127;
        bool lo = d < 64;
        int i0 = d & 63;
        int pb = lo ? base + 64 : base - 64;
        int kt = t >> 5, lq = t & 31;
        #pragma unroll
        for (int j = 0; j < 2; ++j) {
            float xv = kr[base + j] * kinv * kw[base + j];
            float pv = kr[pb + j] * kinv * kw[pb + j];
            float c = cosL[i0 + j];
            float s = sinL[i0 + j];
            float o = lo ? (xv * c - pv * s) : (xv * c + pv * s);
            int dj = d + j;
            int sl = dj >> 4, hi2 = (dj >> 3) & 1, jj = dj & 7;
            size_t oi = ((((size_t)(kh * 64 + kt) * 8 + sl) * 2 + hi2) * 32 + lq) * 8 + jj;
            Ks[oi] = f2bf(o);
        }
    }
}

// ---------------- kernel 3: V -> bf16 swizzled fragment layout ----------------
__global__ __launch_bounds__(256) void v_prep(const float* __restrict__ v,
                                              unsigned short* __restrict__ Vs) {
    __shared__ unsigned short tile[64][80];   // 16B-aligned rows
    int tb = blockIdx.x;   // 32 t-tiles of 64
    int cb = blockIdx.y;   // 8 c-tiles of 64
    int tid = threadIdx.x;
    #pragma unroll 4
    for (int rep = 0; rep < 16; ++rep) {
        int e = rep * 256 + tid;
        int r = e >> 6;    // t within tile
        int c = e & 63;    // col within tile
        tile[c][r] = f2bf(v[(size_t)(tb * 64 + r) * KVD + cb * 64 + c]);
    }
    __syncthreads();
    #pragma unroll
    for (int rep = 0; rep < 2; ++rep) {
        int e = rep * 256 + tid;       // 0..511
        int cc = e >> 3, tg = e & 7;
        int cg = cb * 64 + cc;
        int kh = cg >> 7, crow = cg & 127, db = crow >> 5, lq = crow & 31;
        int t0g = tb * 64 + tg * 8;
        int kt = t0g >> 5, tr = t0g & 31, half = tr >> 4, hi2 = (tr >> 3) & 1;
        size_t o = (((((size_t)(kh * 64 + kt) * 2 + half) * 4 + db) * 2 + hi2) * 32 + lq) * 8;
        *(bf16x8*)(Vs + o) = *(const bf16x8*)(&tile[cc][tg * 8]);
    }
}

// ---------------- kernel 4: w_out f32 -> bf16 ----------------
__global__ __launch_bounds__(256) void w_prep(const float* __restrict__ w,
                                              unsigned short* __restrict__ Wb) {
    size_t idx = ((size_t)blockIdx.x * 256 + threadIdx.x) * 4;
    float4 f = *(const float4*)(w + idx);
    ushort4 o;
    o.x = f2bf(f.x); o.y = f2bf(f.y); o.z = f2bf(f.z); o.w = f2bf(f.w);
    *(ushort4*)(Wb + idx) = o;
}

// ---------------- kernel 5: flash attention, fixed-shift softmax, reg-pipelined ----------------
// p = exp2(s*scale*log2e - B), B=20 constant (scores bounded: RMS-normed Q,K).
// CHUNK=22: total segments = 2016 <= 2048 resident capacity (2 waves/SIMD @176 VGPR)
// -> every wave runs from t~0; wall ~ slowest (22-tile) wave, no residency rounds.
// R9-proven tile loop: dual QK chains, V(t) at top, K(t+1) into alternate buffer.
#define BEXP 20.0f
#define SCALE2 (0.08838834764831845f * 1.4426950408889634f)

#define ATTN_BODY(CUR, NXT)                                                        \
    do {                                                                           \
        const unsigned short* Vt_ = Vbase + (size_t)kt * 4096;                     \
        bf16x8 vb[8];                                                              \
        _Pragma("unroll") for (int x = 0; x < 8; ++x)                              \
            vb[x] = *(const bf16x8*)(Vt_ + x * 512);                               \
        if (kt + 1 < t1) {                                                         \
            const unsigned short* Kn_ = Kbase + (size_t)(kt + 1) * 4096;           \
            _Pragma("unroll") for (int x = 0; x < 8; ++x)                          \
                NXT[x] = *(const bf16x8*)(Kn_ + x * 512);                          \
        }                                                                          \
        f32x16 sa_, sb_;                                                           \
        _Pragma("unroll") for (int r = 0; r < 16; ++r) { sa_[r] = 0.f; sb_[r] = 0.f; } \
        _Pragma("unroll") for (int x = 0; x < 8; x += 2) {                         \
            sa_ = mfma32(CUR[x], qf[x], sa_);                                      \
            sb_ = mfma32(CUR[x + 1], qf[x + 1], sb_);                              \
        }                                                                          \
        float p_[16];                                                              \
        if (kt == nkt - 1) {                                                       \
            int lim = qglob - kt * 32;                                             \
            _Pragma("unroll") for (int r = 0; r < 16; ++r) {                       \
                float e_ = __builtin_amdgcn_exp2f((sa_[r] + sb_[r]) * SCALE2 - BEXP); \
                int off_ = (r & 3) + 8 * (r >> 2) + 4 * hi;                        \
                p_[r] = (off_ <= lim) ? e_ : 0.f;                                  \
                sden4[r & 3] += p_[r];                                             \
            }                                                                      \
        } else {                                                                   \
            _Pragma("unroll") for (int r = 0; r < 16; ++r) {                       \
                p_[r] = __builtin_amdgcn_exp2f((sa_[r] + sb_[r]) * SCALE2 - BEXP); \
                sden4[r & 3] += p_[r];                                             \
            }                                                                      \
        }                                                                          \
        _Pragma("unroll") for (int half = 0; half < 2; ++half) {                   \
            unsigned int a0 = cvtpk(p_[half * 8 + 0], p_[half * 8 + 1]);           \
            unsigned int a1 = cvtpk(p_[half * 8 + 2], p_[half * 8 + 3]);           \
            unsigned int b0 = cvtpk(p_[half * 8 + 4], p_[half * 8 + 5]);           \
            unsigned int b1 = cvtpk(p_[half * 8 + 6], p_[half * 8 + 7]);           \
            uint2v w0 = __builtin_amdgcn_permlane32_swap(a0, b0, false, false);    \
            uint2v w1 = __builtin_amdgcn_permlane32_swap(a1, b1, false, false);    \
            union { unsigned int u[4]; bf16x8 v; } pc;                             \
            pc.u[0] = w0[0]; pc.u[1] = w1[0]; pc.u[2] = w0[1]; pc.u[3] = w1[1];    \
            bf16x8 pf = pc.v;                                                      \
            _Pragma("unroll") for (int db = 0; db < 4; ++db)                       \
                oacc[db] = mfma32(vb[half * 4 + db], pf, oacc[db]);                \
        }                                                                          \
    } while (0)

__global__ __launch_bounds__(64) void attn_fwd11(
    const unsigned short* __restrict__ Qb, const unsigned short* __restrict__ Ks,
    const unsigned short* __restrict__ Vs,
    unsigned short* __restrict__ Opart, float* __restrict__ Lpart,
    unsigned short* __restrict__ Xo, int CHUNK) {
    int qrow = 63 - (int)blockIdx.x;   // heavy blocks first
    int h = blockIdx.y;
    int seg = blockIdx.z;
    int kh = h >> 2;
    int l = threadIdx.x;
    int lq = l & 31, hi = l >> 5;
    int qglob = qrow * 32 + lq;

    int nkt = qrow + 1;
    int t0 = seg * CHUNK;
    int t1 = min(t0 + CHUNK, nkt);
    if (t0 >= t1) return;   // combine knows exactly which segs are used
    size_t idx = (size_t)(h * 64 + qrow) * 4 + seg;

    const unsigned short* Qh = Qb + (size_t)h * T_SEQ * HD;
    const unsigned short* Kbase = Ks + (size_t)kh * 64 * 4096 + l * 8;
    const unsigned short* Vbase = Vs + (size_t)kh * 64 * 4096 + l * 8;

    bf16x8 qf[8];
    #pragma unroll
    for (int sl = 0; sl < 8; ++sl)
        qf[sl] = *(const bf16x8*)(Qh + (size_t)qglob * HD + sl * 16 + hi * 8);

    f32x16 oacc[4];
    #pragma unroll
    for (int db = 0; db < 4; ++db)
        #pragma unroll
        for (int r = 0; r < 16; ++r) oacc[db][r] = 0.f;
    f32x4 sden4 = (f32x4){0.f, 0.f, 0.f, 0.f};

    bf16x8 kA[8], kB[8];
    {
        const unsigned short* K0 = Kbase + (size_t)t0 * 4096;
        #pragma unroll
        for (int x = 0; x < 8; ++x) kA[x] = *(const bf16x8*)(K0 + x * 512);
    }
    int kt = t0;
    while (true) {
        ATTN_BODY(kA, kB);
        if (++kt >= t1) break;
        ATTN_BODY(kB, kA);
        if (++kt >= t1) break;
    }

    float sden = (sden4[0] + sden4[1]) + (sden4[2] + sden4[3]);
    float sden_tot = sden + __shfl_xor(sden, 32);

    if (t0 == 0 && t1 == nkt) {
        // row fits one segment: direct normalized write (no partial round-trip)
        float invs = 1.0f / sden_tot;
        #pragma unroll
        for (int db = 0; db < 4; ++db) {
            #pragma unroll
            for (int r = 0; r < 16; ++r) {
                int d = db * 32 + (r & 3) + 8 * (r >> 2) + 4 * hi;
                Xo[(size_t)qglob * DM + h * HD + d] = f2bf(oacc[db][r] * invs);
            }
        }
        return;
    }
    if (hi == 0) Lpart[idx * 32 + lq] = sden_tot;
    unsigned short* op = Opart + (idx << 12);   // [128 d][32 q]
    #pragma unroll
    for (int db = 0; db < 4; ++db) {
        #pragma unroll
        for (int r = 0; r < 16; ++r) {
            int d = db * 32 + (r & 3) + 8 * (r >> 2) + 4 * hi;
            op[d * 32 + lq] = f2bf(oacc[db][r]);
        }
    }
}

// ---------------- kernel 5b: combine K-split partials (rows with >1 segment) ----------------
__global__ __launch_bounds__(256) void attn_combine(
    const unsigned short* __restrict__ Opart, const float* __restrict__ Lpart,
    unsigned short* __restrict__ Xo, int CHUNK) {
    int qrow = CHUNK + blockIdx.x;   // rows with nkt > CHUNK
    int h = blockIdx.y;
    int tid = threadIdx.x;
    int nkt = qrow + 1;
    int used = (nkt + CHUNK - 1) / CHUNK;
    int base = (h * 64 + qrow) * 4;
    __shared__ float invden[32];
    if (tid < 32) {
        int q = tid;
        float den = 0.f;
        for (int s = 0; s < used; ++s) den += Lpart[(base + s) * 32 + q];
        invden[q] = 1.0f / den;
    }
    __syncthreads();
    int d = tid >> 1, q0 = (tid & 1) * 16;
    float acc[16];
    #pragma unroll
    for (int j = 0; j < 16; ++j) acc[j] = 0.f;
    for (int s = 0; s < used; ++s) {
        const unsigned short* op = Opart + ((size_t)(base + s) << 12) + d * 32 + q0;
        bf16x8 o0 = *(const bf16x8*)(op);
        bf16x8 o1 = *(const bf16x8*)(op + 8);
        #pragma unroll
        for (int j = 0; j < 8; ++j) {
            acc[j]     += bf2f((unsigned short)o0[j]);
            acc[8 + j] += bf2f((unsigned short)o1[j]);
        }
    }
    __shared__ unsigned short xo[32][136];
    #pragma unroll
    for (int j = 0; j < 16; ++j)
        xo[q0 + j][d] = f2bf(acc[j] * invden[q0 + j]);
    __syncthreads();
    int q = tid >> 3, dc = (tid & 7) * 16;
    bf16x8 v0 = *(const bf16x8*)(&xo[q][dc]);
    bf16x8 v1 = *(const bf16x8*)(&xo[q][dc + 8]);
    size_t ro = (size_t)(qrow * 32 + q) * DM + h * HD + dc;
    *(bf16x8*)(Xo + ro) = v0;
    *(bf16x8*)(Xo + ro + 8) = v1;
}

// ---------------- kernel 6: out = X(bf16) @ W^T(bf16) -> f32 ----------------
// 128x64 tile, BK=64, 4 waves (2x2), T14 async-stage pipeline, bijective XCD swizzle.
__global__ __launch_bounds__(256) void outproj2(
    const unsigned short* __restrict__ X, const unsigned short* __restrict__ Wb,
    float* __restrict__ out) {
    __shared__ unsigned short As[128][72];
    __shared__ unsigned short Bs[64][72];
    int tid = threadIdx.x;
    int w = tid >> 6, l = tid & 63;
    int lr = l & 15, lg = l >> 4;
    int wm = w >> 1, wn = w & 1;
    // 512 blocks, 512%8==0: wg=(id&7)*64+(id>>3) is bijective; each XCD gets a
    // contiguous 64-wg slab -> 4 shared B-panels (1MB) stay L2-resident per XCD.
    int id = blockIdx.x;
    int wg = (id & 7) * 64 + (id >> 3);
    int m0 = (wg & 15) * 128, n0 = (wg >> 4) * 64;

    int ar_row[4], ar_col[4], br_row[2], br_col[2];
    #pragma unroll
    for (int qd = 0; qd < 4; ++qd) {
        int c = tid + qd * 256;
        ar_row[qd] = c >> 3; ar_col[qd] = (c & 7) * 8;
    }
    #pragma unroll
    for (int qd = 0; qd < 2; ++qd) {
        int c = tid + qd * 256;
        br_row[qd] = c >> 3; br_col[qd] = (c & 7) * 8;
    }

    f32x4 acc[4][2];
    #pragma unroll
    for (int i = 0; i < 4; ++i)
        #pragma unroll
        for (int j = 0; j < 2; ++j) acc[i][j] = (f32x4){0.f, 0.f, 0.f, 0.f};

    bf16x8 ar[4], br[2];
    #pragma unroll
    for (int qd = 0; qd < 4; ++qd)
        ar[qd] = *(const bf16x8*)(X + (size_t)(m0 + ar_row[qd]) * DM + ar_col[qd]);
    #pragma unroll
    for (int qd = 0; qd < 2; ++qd)
        br[qd] = *(const bf16x8*)(Wb + (size_t)(n0 + br_row[qd]) * DM + br_col[qd]);
    #pragma unroll
    for (int qd = 0; qd < 4; ++qd)
        *(bf16x8*)(&As[ar_row[qd]][ar_col[qd]]) = ar[qd];
    #pragma unroll
    for (int qd = 0; qd < 2; ++qd)
        *(bf16x8*)(&Bs[br_row[qd]][br_col[qd]]) = br[qd];
    __syncthreads();

    for (int t = 0; t < DM / 64; ++t) {
        if (t + 1 < DM / 64) {
            int k0 = (t + 1) * 64;
            #pragma unroll
            for (int qd = 0; qd < 4; ++qd)
                ar[qd] = *(const bf16x8*)(X + (size_t)(m0 + ar_row[qd]) * DM + k0 + ar_col[qd]);
            #pragma unroll
            for (int qd = 0; qd < 2; ++qd)
                br[qd] = *(const bf16x8*)(Wb + (size_t)(n0 + br_row[qd]) * DM + k0 + br_col[qd]);
        }
        #pragma unroll
        for (int ks = 0; ks < 2; ++ks) {
            bf16x8 af[4], bfr[2];
            #pragma unroll
            for (int i = 0; i < 4; ++i)
                af[i] = *(const bf16x8*)(&As[wm * 64 + i * 16 + lr][ks * 32 + lg * 8]);
            #pragma unroll
            for (int j = 0; j < 2; ++j)
                bfr[j] = *(const bf16x8*)(&Bs[wn * 32 + j * 16 + lr][ks * 32 + lg * 8]);
            #pragma unroll
            for (int i = 0; i < 4; ++i)
                #pragma unroll
                for (int j = 0; j < 2; ++j)
                    acc[i][j] = mfma16(af[i], bfr[j], acc[i][j]);
        }
        if (t + 1 < DM / 64) {
            __syncthreads();
            #pragma unroll
            for (int qd = 0; qd < 4; ++qd)
                *(bf16x8*)(&As[ar_row[qd]][ar_col[qd]]) = ar[qd];
            #pragma unroll
            for (int qd = 0; qd < 2; ++qd)
                *(bf16x8*)(&Bs[br_row[qd]][br_col[qd]]) = br[qd];
            __syncthreads();
        }
    }
    #pragma unroll
    for (int i = 0; i < 4; ++i) {
        #pragma unroll
        for (int j = 0; j < 2; ++j) {
            #pragma unroll
            for (int r = 0; r < 4; ++r) {
                int row = m0 + wm * 64 + i * 16 + lg * 4 + r;
                int col = n0 + wn * 32 + j * 16 + lr;
                out[(size_t)row * DM + col] = acc[i][j][r];
            }
        }
    }
}

extern "C" void kernel_launch(void* const* d_in, const int* in_sizes, int n_in,
                              void* d_out, int out_size, void* d_ws, size_t ws_size,
                              hipStream_t stream) {
    const float* q = (const float*)d_in[0];
    const float* k = (const float*)d_in[1];
    const float* v = (const float*)d_in[2];
    const int* pos_ids = (const int*)d_in[4];
    const float* qw = (const float*)d_in[5];
    const float* kw = (const float*)d_in[6];
    const float* wout = (const float*)d_in[7];
    float* out = (float*)d_out;

    char* ws = (char*)d_ws;
    unsigned short* Qb = (unsigned short*)(ws + 0x100000);
    unsigned short* Ks = (unsigned short*)(ws + 0x900000);   // swizzled K, 2MB
    unsigned short* Vs = (unsigned short*)(ws + 0xB00000);   // swizzled V, 2MB
    unsigned short* Wb = (unsigned short*)(ws + 0xD00000);
    unsigned short* Xo = (unsigned short*)(ws + 0x1500000);
    float* Lpart = (float*)(ws + 0x1D00000);                 // 512KB (4 seg slots)
    unsigned short* Opart = (unsigned short*)(ws + 0x1E00000);  // 32MB (4 seg slots)

    // CHUNK=22: Sum_rows ceil(nkt/22) * NH = 2016 blocks <= 2048 resident capacity
    // (2 waves/SIMD at VGPR=176) -> no residency rounds. Max 3 segs/row.
    int CHUNK = (ws_size >= 0x1E00000ull + 4ull * 0x800000ull) ? 22 : 64;
    int zsegs = (CHUNK == 22) ? 3 : 1;

    qk_prep<<<T_SEQ, 256, 0, stream>>>(q, k, qw, kw, pos_ids, Qb, Ks);
    v_prep<<<dim3(T_SEQ / 64, KVD / 64), 256, 0, stream>>>(v, Vs);
    w_prep<<<(DM * DM) / (256 * 4), 256, 0, stream>>>(wout, Wb);
    attn_fwd11<<<dim3(64, NH, zsegs), 64, 0, stream>>>(Qb, Ks, Vs, Opart, Lpart, Xo, CHUNK);
    if (CHUNK == 22)
        attn_combine<<<dim3(64 - 22, NH), 256, 0, stream>>>(Opart, Lpart, Xo, CHUNK);
    outproj2<<<512, 256, 0, stream>>>(Xo, Wb, out);
}

// Round 13
// 95.623 us; speedup vs baseline: 1.0450x; 1.0450x over previous
//
#include <hip/hip_runtime.h>
#include <hip/hip_bf16.h>
#include <math.h>

#define T_SEQ 2048
#define NH 16
#define KVH 4
#define HD 128
#define DM 2048
#define KVD 512

typedef short bf16x8 __attribute__((ext_vector_type(8)));
typedef float f32x4 __attribute__((ext_vector_type(4)));
typedef float f32x16 __attribute__((ext_vector_type(16)));
typedef unsigned int uint2v __attribute__((ext_vector_type(2)));

static __device__ __forceinline__ unsigned short f2bf(float f) {
    unsigned int x = __float_as_uint(f);
    x += 0x7fff + ((x >> 16) & 1);   // round-to-nearest-even
    return (unsigned short)(x >> 16);
}
static __device__ __forceinline__ float bf2f(unsigned short u) {
    return __uint_as_float(((unsigned int)u) << 16);
}

static __device__ __forceinline__ unsigned int cvtpk(float lo, float hi) {
    unsigned int r;
    asm("v_cvt_pk_bf16_f32 %0, %1, %2" : "=v"(r) : "v"(lo), "v"(hi));
    return r;
}

static __device__ __forceinline__ f32x4 mfma16(bf16x8 a, bf16x8 b, f32x4 c) {
    return __builtin_amdgcn_mfma_f32_16x16x32_bf16(a, b, c, 0, 0, 0);
}
static __device__ __forceinline__ f32x16 mfma32(bf16x8 a, bf16x8 b, f32x16 c) {
    return __builtin_amdgcn_mfma_f32_32x32x16_bf16(a, b, c, 0, 0, 0);
}

// async global->LDS, 16B per lane; LDS dest = wave-uniform base + lane*16
static __device__ __forceinline__ void gl_lds16(const unsigned short* g, unsigned short* l) {
    __builtin_amdgcn_global_load_lds(
        (const __attribute__((address_space(1))) unsigned int*)g,
        (__attribute__((address_space(3))) unsigned int*)l,
        16, 0, 0);
}

// Swizzled fragment layouts (lane-contiguous 16B fragments; lane offset = l*8 shorts):
//  Ks[kh][kt][sl][l][j]           : elem (t=kt*32+(l&31), d=sl*16+(l>>5)*8+j)
//  Vs[kh][kt][half*4+db][l][j]    : elem (t=kt*32+half*16+(l>>5)*8+j, c=kh*128+db*32+(l&31))

// ---------------- kernel 2: RMSNorm + RoPE (rope fused); Q row-major, K swizzled ----------------
__global__ __launch_bounds__(256) void qk_prep(
    const float* __restrict__ q, const float* __restrict__ k,
    const float* __restrict__ qw, const float* __restrict__ kw,
    const int* __restrict__ pos_ids,
    unsigned short* __restrict__ Qb, unsigned short* __restrict__ Ks) {
    __shared__ float qr[DM];
    __shared__ float kr[KVD];
    __shared__ float cosL[64], sinL[64];
    __shared__ float redq[4], redk[4];
    int t = blockIdx.x, tid = threadIdx.x;

    float qs = 0.f, ks = 0.f;
    {
        const float* qp = q + (size_t)t * DM + tid * 8;
        float4 v0 = *(const float4*)(qp);
        float4 v1 = *(const float4*)(qp + 4);
        float* dst = qr + tid * 8;
        dst[0] = v0.x; dst[1] = v0.y; dst[2] = v0.z; dst[3] = v0.w;
        dst[4] = v1.x; dst[5] = v1.y; dst[6] = v1.z; dst[7] = v1.w;
        qs = v0.x * v0.x + v0.y * v0.y + v0.z * v0.z + v0.w * v0.w +
             v1.x * v1.x + v1.y * v1.y + v1.z * v1.z + v1.w * v1.w;
        float2 kv = *(const float2*)(k + (size_t)t * KVD + tid * 2);
        kr[tid * 2] = kv.x; kr[tid * 2 + 1] = kv.y;
        ks = kv.x * kv.x + kv.y * kv.y;
    }
    if (tid < 64) {   // fused RoPE table for this token
        float pos = (float)pos_ids[t];
        float inv = powf(10000.0f, -(float)tid * (1.0f / 64.0f));
        float a = pos * inv;
        cosL[tid] = cosf(a);
        sinL[tid] = sinf(a);
    }
    for (int off = 32; off; off >>= 1) {
        qs += __shfl_down(qs, off);
        ks += __shfl_down(ks, off);
    }
    if ((tid & 63) == 0) { redq[tid >> 6] = qs; redk[tid >> 6] = ks; }
    __syncthreads();
    float qinv = rsqrtf((redq[0] + redq[1] + redq[2] + redq[3]) * (1.0f / DM) + 1e-5f);
    float kinv = rsqrtf((redk[0] + redk[1] + redk[2] + redk[3]) * (1.0f / KVD) + 1e-5f);

    {
        int base = tid * 8;
        int h = base >> 7;
        int d = base & 127;
        bool lo = d < 64;
        int i0 = d & 63;
        int pb = lo ? base + 64 : base - 64;
        #pragma unroll
        for (int j = 0; j < 8; ++j) {
            float xv = qr[base + j] * qinv * qw[base + j];
            float pv = qr[pb + j] * qinv * qw[pb + j];
            float c = cosL[i0 + j];
            float s = sinL[i0 + j];
            float o = lo ? (xv * c - pv * s) : (xv * c + pv * s);
            Qb[((size_t)h * T_SEQ + t) * HD + d + j] = f2bf(o);
        }
    }
    {
        int base = tid * 2;
        int kh = base >> 7;
        int d = base & 127;
        bool lo = d < 64;
        int i0 = d & 63;
        int pb = lo ? base + 64 : base - 64;
        int kt = t >> 5, lq = t & 31;
        #pragma unroll
        for (int j = 0; j < 2; ++j) {
            float xv = kr[base + j] * kinv * kw[base + j];
            float pv = kr[pb + j] * kinv * kw[pb + j];
            float c = cosL[i0 + j];
            float s = sinL[i0 + j];
            float o = lo ? (xv * c - pv * s) : (xv * c + pv * s);
            int dj = d + j;
            int sl = dj >> 4, hi2 = (dj >> 3) & 1, jj = dj & 7;
            size_t oi = ((((size_t)(kh * 64 + kt) * 8 + sl) * 2 + hi2) * 32 + lq) * 8 + jj;
            Ks[oi] = f2bf(o);
        }
    }
}

// ---------------- kernel 3: V -> bf16 swizzled fragment layout ----------------
__global__ __launch_bounds__(256) void v_prep(const float* __restrict__ v,
                                              unsigned short* __restrict__ Vs) {
    __shared__ unsigned short tile[64][80];   // 16B-aligned rows
    int tb = blockIdx.x;   // 32 t-tiles of 64
    int cb = blockIdx.y;   // 8 c-tiles of 64
    int tid = threadIdx.x;
    #pragma unroll 4
    for (int rep = 0; rep < 16; ++rep) {
        int e = rep * 256 + tid;
        int r = e >> 6;    // t within tile
        int c = e & 63;    // col within tile
        tile[c][r] = f2bf(v[(size_t)(tb * 64 + r) * KVD + cb * 64 + c]);
    }
    __syncthreads();
    #pragma unroll
    for (int rep = 0; rep < 2; ++rep) {
        int e = rep * 256 + tid;       // 0..511
        int cc = e >> 3, tg = e & 7;
        int cg = cb * 64 + cc;
        int kh = cg >> 7, crow = cg & 127, db = crow >> 5, lq = crow & 31;
        int t0g = tb * 64 + tg * 8;
        int kt = t0g >> 5, tr = t0g & 31, half = tr >> 4, hi2 = (tr >> 3) & 1;
        size_t o = (((((size_t)(kh * 64 + kt) * 2 + half) * 4 + db) * 2 + hi2) * 32 + lq) * 8;
        *(bf16x8*)(Vs + o) = *(const bf16x8*)(&tile[cc][tg * 8]);
    }
}

// ---------------- kernel 4: w_out f32 -> bf16 ----------------
__global__ __launch_bounds__(256) void w_prep(const float* __restrict__ w,
                                              unsigned short* __restrict__ Wb) {
    size_t idx = ((size_t)blockIdx.x * 256 + threadIdx.x) * 4;
    float4 f = *(const float4*)(w + idx);
    ushort4 o;
    o.x = f2bf(f.x); o.y = f2bf(f.y); o.z = f2bf(f.z); o.w = f2bf(f.w);
    *(ushort4*)(Wb + idx) = o;
}

// ---------------- kernel 5: flash attention, 4-wave blocks, LDS-shared K/V ----------------
// Block = 4 waves = the 4 q-heads of one kv-head at one qrow (identical K/V stream,
// identical causal extent -> uniform barriers). K+V tile (16KB) staged ONCE per block
// via global_load_lds (pre-swizzled layout is lane-contiguous), double-buffered.
// Global K/V traffic /4 vs per-wave private reads (the R12 L2-throughput bound).
#define BEXP 20.0f
#define SCALE2 (0.08838834764831845f * 1.4426950408889634f)

#define STAGE(B, KT)                                                               \
    do {                                                                           \
        const unsigned short* kg_ = Kt_g + (size_t)(KT) * 4096;                    \
        const unsigned short* vg_ = Vt_g + (size_t)(KT) * 4096;                    \
        gl_lds16(kg_ + w * 512 + l * 8,        &kv[B][w * 512]);                   \
        gl_lds16(kg_ + 2048 + w * 512 + l * 8, &kv[B][2048 + w * 512]);            \
        gl_lds16(vg_ + w * 512 + l * 8,        &kv[B][4096 + w * 512]);            \
        gl_lds16(vg_ + 2048 + w * 512 + l * 8, &kv[B][6144 + w * 512]);            \
    } while (0)

__global__ __launch_bounds__(256) void attn_fwd12(
    const unsigned short* __restrict__ Qb, const unsigned short* __restrict__ Ks,
    const unsigned short* __restrict__ Vs,
    unsigned short* __restrict__ Opart, float* __restrict__ Lpart,
    unsigned short* __restrict__ Xo, int CHUNK) {
    int qrow = 63 - (int)blockIdx.x;   // heavy blocks first
    int kh = blockIdx.y;               // kv-head
    int seg = blockIdx.z;
    int tid = threadIdx.x;
    int w = tid >> 6, l = tid & 63;
    int h = kh * 4 + w;                // q-head of this wave
    int lq = l & 31, hi = l >> 5;
    int qglob = qrow * 32 + lq;

    int nkt = qrow + 1;
    int t0 = seg * CHUNK;
    int t1 = min(t0 + CHUNK, nkt);
    if (t0 >= t1) return;   // uniform across block (nkt depends only on qrow)
    size_t idx = (size_t)(h * 64 + qrow) * 4 + seg;

    const unsigned short* Qh = Qb + (size_t)h * T_SEQ * HD;
    const unsigned short* Kt_g = Ks + (size_t)kh * 64 * 4096;   // tile stream base
    const unsigned short* Vt_g = Vs + (size_t)kh * 64 * 4096;

    __shared__ unsigned short kv[2][8192];   // [buf][K:0..4095 | V:4096..8191] shorts

    bf16x8 qf[8];
    #pragma unroll
    for (int sl = 0; sl < 8; ++sl)
        qf[sl] = *(const bf16x8*)(Qh + (size_t)qglob * HD + sl * 16 + hi * 8);

    f32x16 oacc[4];
    #pragma unroll
    for (int db = 0; db < 4; ++db)
        #pragma unroll
        for (int r = 0; r < 16; ++r) oacc[db][r] = 0.f;
    f32x4 sden4 = (f32x4){0.f, 0.f, 0.f, 0.f};

    STAGE(0, t0);
    int cur = 0;
    for (int kt = t0; kt < t1; ++kt) {
        __syncthreads();   // staging of kv[cur] complete; prior reads of kv[cur^1] done
        if (kt + 1 < t1) STAGE(cur ^ 1, kt + 1);   // lands during this tile's compute
        const unsigned short* kl = &kv[cur][0] + l * 8;
        const unsigned short* vl = &kv[cur][4096] + l * 8;
        f32x16 sa, sb;
        #pragma unroll
        for (int r = 0; r < 16; ++r) { sa[r] = 0.f; sb[r] = 0.f; }
        #pragma unroll
        for (int x = 0; x < 8; x += 2) {
            bf16x8 k0 = *(const bf16x8*)(kl + x * 512);
            bf16x8 k1 = *(const bf16x8*)(kl + (x + 1) * 512);
            sa = mfma32(k0, qf[x], sa);
            sb = mfma32(k1, qf[x + 1], sb);
        }
        float p_[16];
        if (kt == nkt - 1) {
            int lim = qglob - kt * 32;
            #pragma unroll
            for (int r = 0; r < 16; ++r) {
                float e_ = __builtin_amdgcn_exp2f((sa[r] + sb[r]) * SCALE2 - BEXP);
                int off_ = (r & 3) + 8 * (r >> 2) + 4 * hi;
                p_[r] = (off_ <= lim) ? e_ : 0.f;
                sden4[r & 3] += p_[r];
            }
        } else {
            #pragma unroll
            for (int r = 0; r < 16; ++r) {
                p_[r] = __builtin_amdgcn_exp2f((sa[r] + sb[r]) * SCALE2 - BEXP);
                sden4[r & 3] += p_[r];
            }
        }
        #pragma unroll
        for (int half = 0; half < 2; ++half) {
            unsigned int a0 = cvtpk(p_[half * 8 + 0], p_[half * 8 + 1]);
            unsigned int a1 = cvtpk(p_[half * 8 + 2], p_[half * 8 + 3]);
            unsigned int b0 = cvtpk(p_[half * 8 + 4], p_[half * 8 + 5]);
            unsigned int b1 = cvtpk(p_[half * 8 + 6], p_[half * 8 + 7]);
            uint2v w0 = __builtin_amdgcn_permlane32_swap(a0, b0, false, false);
            uint2v w1 = __builtin_amdgcn_permlane32_swap(a1, b1, false, false);
            union { unsigned int u[4]; bf16x8 v; } pc;
            pc.u[0] = w0[0]; pc.u[1] = w1[0]; pc.u[2] = w0[1]; pc.u[3] = w1[1];
            bf16x8 pf = pc.v;
            #pragma unroll
            for (int db = 0; db < 4; ++db) {
                bf16x8 vf = *(const bf16x8*)(vl + (half * 4 + db) * 512);
                oacc[db] = mfma32(vf, pf, oacc[db]);   // O^T[d][q]
            }
        }
        cur ^= 1;
    }

    float sden = (sden4[0] + sden4[1]) + (sden4[2] + sden4[3]);
    float sden_tot = sden + __shfl_xor(sden, 32);

    if (t0 == 0 && t1 == nkt) {
        // row fits one segment: direct normalized write (no partial round-trip)
        float invs = 1.0f / sden_tot;
        #pragma unroll
        for (int db = 0; db < 4; ++db) {
            #pragma unroll
            for (int r = 0; r < 16; ++r) {
                int d = db * 32 + (r & 3) + 8 * (r >> 2) + 4 * hi;
                Xo[(size_t)qglob * DM + h * HD + d] = f2bf(oacc[db][r] * invs);
            }
        }
        return;
    }
    if (hi == 0) Lpart[idx * 32 + lq] = sden_tot;
    unsigned short* op = Opart + (idx << 12);   // [128 d][32 q]
    #pragma unroll
    for (int db = 0; db < 4; ++db) {
        #pragma unroll
        for (int r = 0; r < 16; ++r) {
            int d = db * 32 + (r & 3) + 8 * (r >> 2) + 4 * hi;
            op[d * 32 + lq] = f2bf(oacc[db][r]);
        }
    }
}

// ---------------- kernel 5b: combine K-split partials (rows with >1 segment) ----------------
__global__ __launch_bounds__(256) void attn_combine(
    const unsigned short* __restrict__ Opart, const float* __restrict__ Lpart,
    unsigned short* __restrict__ Xo, int CHUNK) {
    int qrow = CHUNK + blockIdx.x;   // rows with nkt > CHUNK
    int h = blockIdx.y;
    int tid = threadIdx.x;
    int nkt = qrow + 1;
    int used = (nkt + CHUNK - 1) / CHUNK;
    int base = (h * 64 + qrow) * 4;
    __shared__ float invden[32];
    if (tid < 32) {
        int q = tid;
        float den = 0.f;
        for (int s = 0; s < used; ++s) den += Lpart[(base + s) * 32 + q];
        invden[q] = 1.0f / den;
    }
    __syncthreads();
    int d = tid >> 1, q0 = (tid & 1) * 16;
    float acc[16];
    #pragma unroll
    for (int j = 0; j < 16; ++j) acc[j] = 0.f;
    for (int s = 0; s < used; ++s) {
        const unsigned short* op = Opart + ((size_t)(base + s) << 12) + d * 32 + q0;
        bf16x8 o0 = *(const bf16x8*)(op);
        bf16x8 o1 = *(const bf16x8*)(op + 8);
        #pragma unroll
        for (int j = 0; j < 8; ++j) {
            acc[j]     += bf2f((unsigned short)o0[j]);
            acc[8 + j] += bf2f((unsigned short)o1[j]);
        }
    }
    __shared__ unsigned short xo[32][136];
    #pragma unroll
    for (int j = 0; j < 16; ++j)
        xo[q0 + j][d] = f2bf(acc[j] * invden[q0 + j]);
    __syncthreads();
    int q = tid >> 3, dc = (tid & 7) * 16;
    bf16x8 v0 = *(const bf16x8*)(&xo[q][dc]);
    bf16x8 v1 = *(const bf16x8*)(&xo[q][dc + 8]);
    size_t ro = (size_t)(qrow * 32 + q) * DM + h * HD + dc;
    *(bf16x8*)(Xo + ro) = v0;
    *(bf16x8*)(Xo + ro + 8) = v1;
}

// ---------------- kernel 6: out = X(bf16) @ W^T(bf16) -> f32 ----------------
// 128x64 tile, BK=64, 4 waves (2x2), T14 async-stage pipeline, bijective XCD swizzle.
__global__ __launch_bounds__(256) void outproj2(
    const unsigned short* __restrict__ X, const unsigned short* __restrict__ Wb,
    float* __restrict__ out) {
    __shared__ unsigned short As[128][72];
    __shared__ unsigned short Bs[64][72];
    int tid = threadIdx.x;
    int w = tid >> 6, l = tid & 63;
    int lr = l & 15, lg = l >> 4;
    int wm = w >> 1, wn = w & 1;
    int id = blockIdx.x;
    int wg = (id & 7) * 64 + (id >> 3);
    int m0 = (wg & 15) * 128, n0 = (wg >> 4) * 64;

    int ar_row[4], ar_col[4], br_row[2], br_col[2];
    #pragma unroll
    for (int qd = 0; qd < 4; ++qd) {
        int c = tid + qd * 256;
        ar_row[qd] = c >> 3; ar_col[qd] = (c & 7) * 8;
    }
    #pragma unroll
    for (int qd = 0; qd < 2; ++qd) {
        int c = tid + qd * 256;
        br_row[qd] = c >> 3; br_col[qd] = (c & 7) * 8;
    }

    f32x4 acc[4][2];
    #pragma unroll
    for (int i = 0; i < 4; ++i)
        #pragma unroll
        for (int j = 0; j < 2; ++j) acc[i][j] = (f32x4){0.f, 0.f, 0.f, 0.f};

    bf16x8 ar[4], br[2];
    #pragma unroll
    for (int qd = 0; qd < 4; ++qd)
        ar[qd] = *(const bf16x8*)(X + (size_t)(m0 + ar_row[qd]) * DM + ar_col[qd]);
    #pragma unroll
    for (int qd = 0; qd < 2; ++qd)
        br[qd] = *(const bf16x8*)(Wb + (size_t)(n0 + br_row[qd]) * DM + br_col[qd]);
    #pragma unroll
    for (int qd = 0; qd < 4; ++qd)
        *(bf16x8*)(&As[ar_row[qd]][ar_col[qd]]) = ar[qd];
    #pragma unroll
    for (int qd = 0; qd < 2; ++qd)
        *(bf16x8*)(&Bs[br_row[qd]][br_col[qd]]) = br[qd];
    __syncthreads();

    for (int t = 0; t < DM / 64; ++t) {
        if (t + 1 < DM / 64) {
            int k0 = (t + 1) * 64;
            #pragma unroll
            for (int qd = 0; qd < 4; ++qd)
                ar[qd] = *(const bf16x8*)(X + (size_t)(m0 + ar_row[qd]) * DM + k0 + ar_col[qd]);
            #pragma unroll
            for (int qd = 0; qd < 2; ++qd)
                br[qd] = *(const bf16x8*)(Wb + (size_t)(n0 + br_row[qd]) * DM + k0 + br_col[qd]);
        }
        #pragma unroll
        for (int ks = 0; ks < 2; ++ks) {
            bf16x8 af[4], bfr[2];
            #pragma unroll
            for (int i = 0; i < 4; ++i)
                af[i] = *(const bf16x8*)(&As[wm * 64 + i * 16 + lr][ks * 32 + lg * 8]);
            #pragma unroll
            for (int j = 0; j < 2; ++j)
                bfr[j] = *(const bf16x8*)(&Bs[wn * 32 + j * 16 + lr][ks * 32 + lg * 8]);
            #pragma unroll
            for (int i = 0; i < 4; ++i)
                #pragma unroll
                for (int j = 0; j < 2; ++j)
                    acc[i][j] = mfma16(af[i], bfr[j], acc[i][j]);
        }
        if (t + 1 < DM / 64) {
            __syncthreads();
            #pragma unroll
            for (int qd = 0; qd < 4; ++qd)
                *(bf16x8*)(&As[ar_row[qd]][ar_col[qd]]) = ar[qd];
            #pragma unroll
            for (int qd = 0; qd < 2; ++qd)
                *(bf16x8*)(&Bs[br_row[qd]][br_col[qd]]) = br[qd];
            __syncthreads();
        }
    }
    #pragma unroll
    for (int i = 0; i < 4; ++i) {
        #pragma unroll
        for (int j = 0; j < 2; ++j) {
            #pragma unroll
            for (int r = 0; r < 4; ++r) {
                int row = m0 + wm * 64 + i * 16 + lg * 4 + r;
                int col = n0 + wn * 32 + j * 16 + lr;
                out[(size_t)row * DM + col] = acc[i][j][r];
            }
        }
    }
}

extern "C" void kernel_launch(void* const* d_in, const int* in_sizes, int n_in,
                              void* d_out, int out_size, void* d_ws, size_t ws_size,
                              hipStream_t stream) {
    const float* q = (const float*)d_in[0];
    const float* k = (const float*)d_in[1];
    const float* v = (const float*)d_in[2];
    const int* pos_ids = (const int*)d_in[4];
    const float* qw = (const float*)d_in[5];
    const float* kw = (const float*)d_in[6];
    const float* wout = (const float*)d_in[7];
    float* out = (float*)d_out;

    char* ws = (char*)d_ws;
    unsigned short* Qb = (unsigned short*)(ws + 0x100000);
    unsigned short* Ks = (unsigned short*)(ws + 0x900000);   // swizzled K, 2MB
    unsigned short* Vs = (unsigned short*)(ws + 0xB00000);   // swizzled V, 2MB
    unsigned short* Wb = (unsigned short*)(ws + 0xD00000);
    unsigned short* Xo = (unsigned short*)(ws + 0x1500000);
    float* Lpart = (float*)(ws + 0x1D00000);                 // 512KB (4 seg slots)
    unsigned short* Opart = (unsigned short*)(ws + 0x1E00000);  // 32MB (4 seg slots)

    // CHUNK=22: 126 segment-blocks per kv-head x 4 = 504 blocks <= 512 resident
    // capacity (2 blocks/CU at 32KB LDS + ~2 waves/SIMD). Max 3 segs/row.
    int CHUNK = (ws_size >= 0x1E00000ull + 4ull * 0x800000ull) ? 22 : 64;
    int zsegs = (CHUNK == 22) ? 3 : 1;

    qk_prep<<<T_SEQ, 256, 0, stream>>>(q, k, qw, kw, pos_ids, Qb, Ks);
    v_prep<<<dim3(T_SEQ / 64, KVD / 64), 256, 0, stream>>>(v, Vs);
    w_prep<<<(DM * DM) / (256 * 4), 256, 0, stream>>>(wout, Wb);
    attn_fwd12<<<dim3(64, KVH, zsegs), 256, 0, stream>>>(Qb, Ks, Vs, Opart, Lpart, Xo, CHUNK);
    if (CHUNK == 22)
        attn_combine<<<dim3(64 - 22, NH), 256, 0, stream>>>(Opart, Lpart, Xo, CHUNK);
    outproj2<<<512, 256, 0, stream>>>(Xo, Wb, out);
}